// Round 10
// baseline (218.835 us; speedup 1.0000x reference)
//
#include <hip/hip_runtime.h>

typedef __attribute__((ext_vector_type(8))) short bf16x8;
typedef __attribute__((ext_vector_type(4))) float f32x4;
typedef __attribute__((ext_vector_type(8))) unsigned short u16x8;
typedef unsigned int u32;
typedef unsigned short u16;

#define CIN 512
#define CO  512
#define HH  64
#define WW  64
#define BB  8
#define HP  66
#define WPAD 68
#define HPW (HP*WPAD)
#define KK  4608  // CIN*9

#define SIG_BYTES  (BB*CO*4)                       // 16384
#define WMOD_ELEMS ((size_t)BB*9*64*CO*8)          // 18,874,368
#define WMOD_BYTES (WMOD_ELEMS*2)                  // 37,748,736
#define IMGT_ELEMS ((size_t)BB*64*HP*WPAD*8)       // 18,382,848  [b][grp64][66][68][8]
#define IMGT_BYTES (IMGT_ELEMS*2)                  // 36,765,696
#define WS_NEED    ((size_t)SIG_BYTES + WMOD_BYTES + IMGT_BYTES)

__device__ __forceinline__ u16 f2bf(float f) {
  union { float f; u32 u; } v; v.f = f;
  u32 r = (v.u + 0x7FFFu + ((v.u >> 16) & 1u)) >> 16;  // RNE
  return (u16)r;
}

// ---------------- K1: sigma[b][o] = rsqrt(sum_i,t (w*(s+1))^2 + eps) ----------
__global__ void k_sigma(const float* __restrict__ weight, const float* __restrict__ s,
                        float* __restrict__ sigma) {
  int o = blockIdx.x;          // 512 blocks
  int tid = threadIdx.x;       // 256 threads
  const float* wrow = weight + (size_t)o * KK;
  float acc[BB];
#pragma unroll
  for (int b = 0; b < BB; ++b) acc[b] = 0.f;
  for (int e = tid; e < KK; e += 256) {
    float w = wrow[e];
    float w2 = w * w;
    int i = e / 9;
#pragma unroll
    for (int b = 0; b < BB; ++b) {
      float m = s[b * CIN + i] + 1.0f;
      acc[b] += w2 * m * m;
    }
  }
#pragma unroll
  for (int b = 0; b < BB; ++b) {
#pragma unroll
    for (int off = 32; off >= 1; off >>= 1)
      acc[b] += __shfl_down(acc[b], off);
  }
  __shared__ float red[4][BB];
  int wv = tid >> 6, ln = tid & 63;
  if (ln == 0) {
#pragma unroll
    for (int b = 0; b < BB; ++b) red[wv][b] = acc[b];
  }
  __syncthreads();
  if (tid < BB) {
    float t = red[0][tid] + red[1][tid] + red[2][tid] + red[3][tid];
    sigma[tid * CO + o] = rsqrtf(t + 1e-8f);
  }
}

// ------------- K2: wmod[b][t][kg][o][8] bf16, LDS-staged coalesced ------------
__global__ __launch_bounds__(256) void k_wmod(const float* __restrict__ weight,
                                              const float* __restrict__ s,
                                              const float* __restrict__ sigma,
                                              u16* __restrict__ wmod) {
  __shared__ float lw[16][577];
  int bid = blockIdx.x;        // 256 = 32 oc * 8 ic
  int oc = bid & 31, ic = bid >> 5;
  int o0 = oc * 16;
  int tid = threadIdx.x;
  const float* wsrc = weight + (size_t)o0 * KK + ic * 576;
#pragma unroll
  for (int k = 0; k < 9; ++k) {
    int f4 = tid + k * 256;            // 0..2303
    int row = f4 / 144;                // 144 float4 per row
    int col = f4 - row * 144;
    float4 v = *(const float4*)(wsrc + (size_t)row * KK + col * 4);
    lw[row][col*4+0]=v.x; lw[row][col*4+1]=v.y; lw[row][col*4+2]=v.z; lw[row][col*4+3]=v.w;
  }
  __syncthreads();
  int o_l = tid & 15, kg_l = (tid >> 4) & 7;
#pragma unroll
  for (int k = 0; k < 36; ++k) {
    int bt = k * 2 + (tid >> 7);       // 0..71
    int b = bt / 9;
    int t = bt - b * 9;
    int o = o0 + o_l;
    float sig = sigma[b * CO + o];
    u16x8 ov;
#pragma unroll
    for (int j = 0; j < 8; ++j) {
      int il = kg_l * 8 + j;
      float w = lw[o_l][il * 9 + t];
      float m = s[b * CIN + ic * 64 + il] + 1.0f;
      ov[j] = f2bf(w * m * sig);
    }
    *(u16x8*)(wmod + ((size_t)(bt * 64 + (ic * 8 + kg_l)) * CO + o) * 8) = ov;
  }
}

// ------------- K3a: zero pad border of imgt [b][grp][66][68][8] --------------
__global__ void k_pad(u16* __restrict__ imgt) {
  int gid = blockIdx.x * 256 + threadIdx.x;   // 528*256 = 135168 vec-stores
  int grp = gid & 63;
  int pos = gid >> 6;                         // 0..2111 = 8b * 264
  int b = pos / 264;
  int pr = pos - b * 264;
  int yp, xp;
  if (pr < 136) { yp = (pr < 68) ? 0 : 65; xp = (pr < 68) ? pr : pr - 68; }
  else { int q = pr - 136; yp = 1 + (q >> 1); xp = (q & 1) ? 67 : 0; }
  u16x8 z = {0,0,0,0,0,0,0,0};
  *(u16x8*)(imgt + (((size_t)(b * 64 + grp) * HP + yp) * WPAD + xp) * 8) = z;
}

// ------------- K3b: imgt[b][grp(64)][yp(66)][xp(68)][8ch] bf16, interior ------
__global__ void k_imgt(const float* __restrict__ img, u16* __restrict__ imgt) {
  int bid = blockIdx.x;        // 8*64*2*8 = 8192 blocks
  int ic = bid & 7;  int r = bid >> 3;
  int xc = r & 1;    r >>= 1;
  int y  = r & 63;   int b = r >> 6;
  int tid = threadIdx.x;
  __shared__ float lt[64][33];
  {
    int ii = tid >> 2, xq = tid & 3;
    const float* src = img + (((size_t)(b * CIN + ic * 64 + ii)) * HH + y) * WW + xc * 32 + xq * 8;
    float4 v0 = *(const float4*)src;
    float4 v1 = *(const float4*)(src + 4);
    int xb = xq * 8;
    lt[ii][xb+0]=v0.x; lt[ii][xb+1]=v0.y; lt[ii][xb+2]=v0.z; lt[ii][xb+3]=v0.w;
    lt[ii][xb+4]=v1.x; lt[ii][xb+5]=v1.y; lt[ii][xb+6]=v1.z; lt[ii][xb+7]=v1.w;
  }
  __syncthreads();
  int xl = tid >> 3, iq = tid & 7;
  u16x8 ov;
#pragma unroll
  for (int j = 0; j < 8; ++j) ov[j] = f2bf(lt[iq*8+j][xl]);
  size_t dst = (((size_t)(b * 64 + ic * 8 + iq) * HP + (y + 1)) * WPAD + (xc * 32 + xl + 1)) * 8;
  *(u16x8*)(imgt + dst) = ov;
}

// --- K4: 4-wave blocks, 2 blocks/CU (independent overlap), c-outer/t-inner ----
__device__ __forceinline__ void async16(const u16* g, void* lds) {
  __builtin_amdgcn_global_load_lds((const __attribute__((address_space(1))) u32*)g,
                                   (__attribute__((address_space(3))) u32*)lds, 16, 0, 0);
}

__global__ __launch_bounds__(256, 2) void k_conv(const u16* __restrict__ wmod,
                                                 const u16* __restrict__ imgt,
                                                 float* __restrict__ out) {
  __shared__ alignas(16) u16 abuf[2][16384];     // 2 x 32KB A-tiles (256o x 64k, swz)
  int bid0 = blockIdx.x;                          // 512 = 8b * 2ot * 32pt
  int bid  = (bid0 & 7) * 64 + (bid0 >> 3);       // XCD-chunked: each XCD = one b
  int b  = bid >> 6;
  int ot = (bid >> 5) & 1;
  int pt = bid & 31;
  int y0 = pt * 2, obase = ot * 256;
  int tid = threadIdx.x;                          // 256
  int wave = tid >> 6, lane = tid & 63;
  int wm = wave >> 1, wn = wave & 1;              // 2 o-halves x 2 y-rows
  int col0 = lane & 15, kg = lane >> 4;

  // A-stage: 8 chunks/thread; linear LDS dest W, inverse-swizzled global source.
  // Swizzle (involution on full byte addr): phys = logical ^ (((addr>>7)&7)<<4).
  const u16* asrc[8];
  int wq[8];
#pragma unroll
  for (int q = 0; q < 8; ++q) {
    int W = (tid + q * 256) * 16;
    int L = W ^ (((W >> 7) & 7) << 4);
    int o = L >> 7;
    int kgl = (L >> 4) & 7;
    wq[q] = W;
    asrc[q] = wmod + ((size_t)(b * 576 + kgl) * 512 + obase + o) * 8;
  }

  // B: per-lane global base (r5-proven addressing)
  const u16* pB = imgt + (((size_t)(b * 64 + kg) * HP + (y0 + wn)) * WPAD + col0) * 8;

  // A ds_read: row field added cleanly; XOR only on bits 4-6 (k-chunk field).
  int arow = (wm * 128 + col0) * 128;
  int xm   = (col0 & 7) << 4;
  int inn0 = (kg * 16) ^ xm;          // kk=0 chunk offset within row
  int inn1 = (kg * 16 + 64) ^ xm;     // kk=1 chunk offset within row

  f32x4 zero = {0.f, 0.f, 0.f, 0.f};
  f32x4 acc[8][4];
#pragma unroll
  for (int i = 0; i < 8; ++i)
#pragma unroll
    for (int j = 0; j < 4; ++j) acc[i][j] = zero;

  bf16x8 BA[4], BB_[4], B1[4];

// Stage A-tile of (channel-chunk cv_, tap tv_): kg rows tv_*64 + cv_*8 .. +7
#define STAGE(cv_, tv_, bufsel) do { \
  const size_t aoff_ = (size_t)((tv_) * 64 + (cv_) * 8) * 4096; \
  _Pragma("unroll") \
  for (int q = 0; q < 8; ++q) \
    async16(asrc[q] + aoff_, (void*)((char*)&abuf[bufsel][0] + wq[q])); \
} while (0)

#define BLOAD(dst, cv_, tv_, kk) do { \
  int ky_ = ((tv_) >= 6) ? 2 : (((tv_) >= 3) ? 1 : 0); \
  int kx_ = (tv_) - 3 * ky_; \
  const u16* pb_ = pB + ((size_t)((cv_) * 8 + (kk) * 4) * HPW + ky_ * WPAD + kx_) * 8; \
  dst[0] = *(const bf16x8*)(pb_ + 0 * 128); \
  dst[1] = *(const bf16x8*)(pb_ + 1 * 128); \
  dst[2] = *(const bf16x8*)(pb_ + 2 * 128); \
  dst[3] = *(const bf16x8*)(pb_ + 3 * 128); \
} while (0)

#define CLUSTER(bufsel, h, kk, BR) do { \
  const char* ab_ = (const char*)&abuf[bufsel][0] + arow + ((kk) ? inn1 : inn0); \
  bf16x8 a0 = *(const bf16x8*)(ab_ + ((h) * 4 + 0) * 2048); \
  bf16x8 a1 = *(const bf16x8*)(ab_ + ((h) * 4 + 1) * 2048); \
  bf16x8 a2 = *(const bf16x8*)(ab_ + ((h) * 4 + 2) * 2048); \
  bf16x8 a3 = *(const bf16x8*)(ab_ + ((h) * 4 + 3) * 2048); \
  __builtin_amdgcn_s_setprio(1); \
  _Pragma("unroll") \
  for (int an = 0; an < 4; ++an) { \
    acc[(h)*4+0][an] = __builtin_amdgcn_mfma_f32_16x16x32_bf16(a0, BR[an], acc[(h)*4+0][an], 0, 0, 0); \
    acc[(h)*4+1][an] = __builtin_amdgcn_mfma_f32_16x16x32_bf16(a1, BR[an], acc[(h)*4+1][an], 0, 0, 0); \
    acc[(h)*4+2][an] = __builtin_amdgcn_mfma_f32_16x16x32_bf16(a2, BR[an], acc[(h)*4+2][an], 0, 0, 0); \
    acc[(h)*4+3][an] = __builtin_amdgcn_mfma_f32_16x16x32_bf16(a3, BR[an], acc[(h)*4+3][an], 0, 0, 0); \
  } \
  __builtin_amdgcn_s_setprio(0); \
} while (0)

// One K-step (chunk cv, tap tv): 4 quadrant phases, 1 barrier, vmcnt never 0.
// Issue order: [stage(next) x8][B-loads x8]; B1's register use force-retires
// the stage (in-order); end vmcnt(4) keeps 4 B-loads in flight across barrier.
#define STEP(k_, BK0, BKN) do { \
  const int bufsel = (k_) & 1; \
  const int cv = c0 + (k_) / 9, tv = (k_) % 9; \
  int cn = c0 + ((k_) + 1) / 9, tn = ((k_) + 1) % 9; \
  if ((k_) == 17 && c0 == 6) { cn = 7; tn = 8; }   /* clamp: no OOB prefetch */ \
  STAGE(cn, tn, bufsel ^ 1); \
  __builtin_amdgcn_sched_barrier(0); \
  BLOAD(B1, cv, tv, 1); \
  CLUSTER(bufsel, 0, 0, BK0); \
  BLOAD(BKN, cn, tn, 0); \
  CLUSTER(bufsel, 1, 0, BK0); \
  CLUSTER(bufsel, 0, 1, B1); \
  CLUSTER(bufsel, 1, 1, B1); \
  asm volatile("s_waitcnt vmcnt(4)" ::: "memory"); \
  __builtin_amdgcn_s_barrier(); \
  __builtin_amdgcn_sched_barrier(0); \
} while (0)

  // prologue: stage step (c=0,t=0), load B(0,0,kk0); counted wait
  STAGE(0, 0, 0);
  __builtin_amdgcn_sched_barrier(0);
  BLOAD(BA, 0, 0, 0);
  asm volatile("s_waitcnt vmcnt(4)" ::: "memory");
  __builtin_amdgcn_s_barrier();
  __builtin_amdgcn_sched_barrier(0);

  // 72 steps: c (channel-chunk) OUTER, t (tap) INNER -> B slice stays hot in
  // XCD-L2 across the 9-tap resweep. c unrolled by 2 (18 steps) for E/O parity.
  for (int jj = 0; jj < 4; ++jj) {
    const int c0 = 2 * jj;
    STEP(0,  BA,  BB_);  STEP(1,  BB_, BA);
    STEP(2,  BA,  BB_);  STEP(3,  BB_, BA);
    STEP(4,  BA,  BB_);  STEP(5,  BB_, BA);
    STEP(6,  BA,  BB_);  STEP(7,  BB_, BA);
    STEP(8,  BA,  BB_);  STEP(9,  BB_, BA);
    STEP(10, BA,  BB_);  STEP(11, BB_, BA);
    STEP(12, BA,  BB_);  STEP(13, BB_, BA);
    STEP(14, BA,  BB_);  STEP(15, BB_, BA);
    STEP(16, BA,  BB_);  STEP(17, BB_, BA);
  }
#undef STEP
#undef CLUSTER
#undef BLOAD
#undef STAGE

  int y = y0 + wn;
#pragma unroll
  for (int am = 0; am < 8; ++am) {
    int o = obase + wm * 128 + am * 16 + kg * 4;   // row = (lane>>4)*4 + reg
#pragma unroll
    for (int an = 0; an < 4; ++an) {
      int x = an * 16 + col0;                       // col = lane&15
      float* op = out + (((size_t)(b * CO + o)) * HH + y) * WW + x;
#pragma unroll
      for (int rg = 0; rg < 4; ++rg)
        op[(size_t)rg * HH * WW] = acc[am][an][rg];
    }
  }
}

// ---------------- Fallback (ws too small): naive but correct ------------------
__global__ void k_naive(const float* __restrict__ img, const float* __restrict__ s,
                        const float* __restrict__ weight, const float* __restrict__ sigma,
                        float* __restrict__ out) {
  int bid = blockIdx.x;          // 8*512*64, 64 threads
  int y = bid & 63; int r = bid >> 6; int o = r & 511; int b = r >> 9;
  int x = threadIdx.x;
  float sig = sigma[b * CO + o];
  float acc = 0.f;
  for (int i = 0; i < CIN; ++i) {
    float m = s[b * CIN + i] + 1.0f;
    const float* wp = weight + ((size_t)o * CIN + i) * 9;
    const float* ip = img + ((size_t)(b * CIN + i)) * HH * WW;
#pragma unroll
    for (int ky = 0; ky < 3; ++ky) {
      int yy = y + ky - 1;
      if (yy < 0 || yy > 63) continue;
#pragma unroll
      for (int kx = 0; kx < 3; ++kx) {
        int xx = x + kx - 1;
        float iv = (xx >= 0 && xx < 64) ? ip[yy * 64 + xx] : 0.f;
        acc += wp[ky * 3 + kx] * m * iv;
      }
    }
  }
  out[((size_t)(b * CO + o) * HH + y) * WW + x] = acc * sig;
}

extern "C" void kernel_launch(void* const* d_in, const int* in_sizes, int n_in,
                              void* d_out, int out_size, void* d_ws, size_t ws_size,
                              hipStream_t stream) {
  const float* img    = (const float*)d_in[0];
  const float* s      = (const float*)d_in[1];
  const float* weight = (const float*)d_in[2];
  float* out = (float*)d_out;
  char* ws = (char*)d_ws;
  float* sigma = (float*)ws;

  if (ws_size >= WS_NEED) {
    u16* wmod = (u16*)(ws + SIG_BYTES);
    u16* imgt = (u16*)(ws + SIG_BYTES + WMOD_BYTES);
    k_sigma<<<512, 256, 0, stream>>>(weight, s, sigma);
    k_wmod<<<256, 256, 0, stream>>>(weight, s, sigma, wmod);
    k_pad<<<528, 256, 0, stream>>>(imgt);
    k_imgt<<<8192, 256, 0, stream>>>(img, imgt);
    k_conv<<<512, 256, 0, stream>>>(wmod, imgt, out);
  } else {
    k_sigma<<<512, 256, 0, stream>>>(weight, s, sigma);
    k_naive<<<BB * CO * HH, 64, 0, stream>>>(img, s, weight, sigma, out);
  }
}

// Round 11
// 194.774 us; speedup vs baseline: 1.1235x; 1.1235x over previous
//
#include <hip/hip_runtime.h>

typedef __attribute__((ext_vector_type(8))) short bf16x8;
typedef __attribute__((ext_vector_type(4))) float f32x4;
typedef __attribute__((ext_vector_type(8))) unsigned short u16x8;
typedef unsigned int u32;
typedef unsigned short u16;

#define CIN 512
#define CO  512
#define HH  64
#define WW  64
#define BB  8
#define HP  66
#define WPAD 68
#define HPW (HP*WPAD)
#define KK  4608  // CIN*9

#define SIG_BYTES  (BB*CO*4)                       // 16384
#define WMOD_ELEMS ((size_t)BB*9*64*CO*8)          // 18,874,368
#define WMOD_BYTES (WMOD_ELEMS*2)                  // 37,748,736
#define IMGT_ELEMS ((size_t)BB*64*HP*WPAD*8)       // 18,382,848  [b][grp64][66][68][8]
#define IMGT_BYTES (IMGT_ELEMS*2)                  // 36,765,696
#define WS_NEED    ((size_t)SIG_BYTES + WMOD_BYTES + IMGT_BYTES)

__device__ __forceinline__ u16 f2bf(float f) {
  union { float f; u32 u; } v; v.f = f;
  u32 r = (v.u + 0x7FFFu + ((v.u >> 16) & 1u)) >> 16;  // RNE
  return (u16)r;
}

// ---------------- K1: sigma[b][o] = rsqrt(sum_i,t (w*(s+1))^2 + eps) ----------
__global__ void k_sigma(const float* __restrict__ weight, const float* __restrict__ s,
                        float* __restrict__ sigma) {
  int o = blockIdx.x;          // 512 blocks
  int tid = threadIdx.x;       // 256 threads
  const float* wrow = weight + (size_t)o * KK;
  float acc[BB];
#pragma unroll
  for (int b = 0; b < BB; ++b) acc[b] = 0.f;
  for (int e = tid; e < KK; e += 256) {
    float w = wrow[e];
    float w2 = w * w;
    int i = e / 9;
#pragma unroll
    for (int b = 0; b < BB; ++b) {
      float m = s[b * CIN + i] + 1.0f;
      acc[b] += w2 * m * m;
    }
  }
#pragma unroll
  for (int b = 0; b < BB; ++b) {
#pragma unroll
    for (int off = 32; off >= 1; off >>= 1)
      acc[b] += __shfl_down(acc[b], off);
  }
  __shared__ float red[4][BB];
  int wv = tid >> 6, ln = tid & 63;
  if (ln == 0) {
#pragma unroll
    for (int b = 0; b < BB; ++b) red[wv][b] = acc[b];
  }
  __syncthreads();
  if (tid < BB) {
    float t = red[0][tid] + red[1][tid] + red[2][tid] + red[3][tid];
    sigma[tid * CO + o] = rsqrtf(t + 1e-8f);
  }
}

// ------------- K2: wmod[b][t][kg][o][8] bf16, LDS-staged coalesced ------------
__global__ __launch_bounds__(256) void k_wmod(const float* __restrict__ weight,
                                              const float* __restrict__ s,
                                              const float* __restrict__ sigma,
                                              u16* __restrict__ wmod) {
  __shared__ float lw[16][577];
  int bid = blockIdx.x;        // 256 = 32 oc * 8 ic
  int oc = bid & 31, ic = bid >> 5;
  int o0 = oc * 16;
  int tid = threadIdx.x;
  const float* wsrc = weight + (size_t)o0 * KK + ic * 576;
#pragma unroll
  for (int k = 0; k < 9; ++k) {
    int f4 = tid + k * 256;            // 0..2303
    int row = f4 / 144;                // 144 float4 per row
    int col = f4 - row * 144;
    float4 v = *(const float4*)(wsrc + (size_t)row * KK + col * 4);
    lw[row][col*4+0]=v.x; lw[row][col*4+1]=v.y; lw[row][col*4+2]=v.z; lw[row][col*4+3]=v.w;
  }
  __syncthreads();
  int o_l = tid & 15, kg_l = (tid >> 4) & 7;
#pragma unroll
  for (int k = 0; k < 36; ++k) {
    int bt = k * 2 + (tid >> 7);       // 0..71
    int b = bt / 9;
    int t = bt - b * 9;
    int o = o0 + o_l;
    float sig = sigma[b * CO + o];
    u16x8 ov;
#pragma unroll
    for (int j = 0; j < 8; ++j) {
      int il = kg_l * 8 + j;
      float w = lw[o_l][il * 9 + t];
      float m = s[b * CIN + ic * 64 + il] + 1.0f;
      ov[j] = f2bf(w * m * sig);
    }
    *(u16x8*)(wmod + ((size_t)(bt * 64 + (ic * 8 + kg_l)) * CO + o) * 8) = ov;
  }
}

// ------------- K3a: zero pad border of imgt [b][grp][66][68][8] --------------
__global__ void k_pad(u16* __restrict__ imgt) {
  int gid = blockIdx.x * 256 + threadIdx.x;   // 528*256 = 135168 vec-stores
  int grp = gid & 63;
  int pos = gid >> 6;                         // 0..2111 = 8b * 264
  int b = pos / 264;
  int pr = pos - b * 264;
  int yp, xp;
  if (pr < 136) { yp = (pr < 68) ? 0 : 65; xp = (pr < 68) ? pr : pr - 68; }
  else { int q = pr - 136; yp = 1 + (q >> 1); xp = (q & 1) ? 67 : 0; }
  u16x8 z = {0,0,0,0,0,0,0,0};
  *(u16x8*)(imgt + (((size_t)(b * 64 + grp) * HP + yp) * WPAD + xp) * 8) = z;
}

// ------------- K3b: imgt[b][grp(64)][yp(66)][xp(68)][8ch] bf16, interior ------
__global__ void k_imgt(const float* __restrict__ img, u16* __restrict__ imgt) {
  int bid = blockIdx.x;        // 8*64*2*8 = 8192 blocks
  int ic = bid & 7;  int r = bid >> 3;
  int xc = r & 1;    r >>= 1;
  int y  = r & 63;   int b = r >> 6;
  int tid = threadIdx.x;
  __shared__ float lt[64][33];
  {
    int ii = tid >> 2, xq = tid & 3;
    const float* src = img + (((size_t)(b * CIN + ic * 64 + ii)) * HH + y) * WW + xc * 32 + xq * 8;
    float4 v0 = *(const float4*)src;
    float4 v1 = *(const float4*)(src + 4);
    int xb = xq * 8;
    lt[ii][xb+0]=v0.x; lt[ii][xb+1]=v0.y; lt[ii][xb+2]=v0.z; lt[ii][xb+3]=v0.w;
    lt[ii][xb+4]=v1.x; lt[ii][xb+5]=v1.y; lt[ii][xb+6]=v1.z; lt[ii][xb+7]=v1.w;
  }
  __syncthreads();
  int xl = tid >> 3, iq = tid & 7;
  u16x8 ov;
#pragma unroll
  for (int j = 0; j < 8; ++j) ov[j] = f2bf(lt[iq*8+j][xl]);
  size_t dst = (((size_t)(b * 64 + ic * 8 + iq) * HP + (y + 1)) * WPAD + (xc * 32 + xl + 1)) * 8;
  *(u16x8*)(imgt + dst) = ov;
}

// ------- K4: r5 structure (3-tap groups, A dbuf LDS) + A-reg E/O prefetch -----
__device__ __forceinline__ void async16(const u16* g, void* lds) {
  __builtin_amdgcn_global_load_lds((const __attribute__((address_space(1))) u32*)g,
                                   (__attribute__((address_space(3))) u32*)lds, 16, 0, 0);
}

__global__ __launch_bounds__(512, 2) void k_conv(const u16* __restrict__ wmod,
                                                 const u16* __restrict__ imgt,
                                                 float* __restrict__ out) {
  __shared__ alignas(16) u16 abuf[2][3][8192];   // 2 x (3 taps x 16KB) = 96KB
  int bid0 = blockIdx.x;                          // 256 = 8b * 2ot * 16pt
  int bid  = (bid0 & 7) * 32 + (bid0 >> 3);       // XCD-chunked: each XCD = one b
  int b  = bid >> 5;
  int ot = (bid >> 4) & 1;
  int pt = bid & 15;
  int y0 = pt * 4, obase = ot * 256;
  int tid = threadIdx.x;                          // 512
  int wave = tid >> 6, lane = tid & 63;
  int wm = wave >> 2, wn = wave & 3;              // 2 o-halves x 4 y-rows
  int col0 = lane & 15, kg = lane >> 4;

  // A-stage source: thread covers chunks tid (kg4=tid>>8) and tid+512 (kg4+2)
  const u16* awsrc0 = wmod + (((size_t)(b * 576 + (tid >> 8))) * 512 + obase + (tid & 255)) * 8;
  const u16* awsrc1 = awsrc0 + 2 * 512 * 8;

  // B base: imgt[(b*64+kg)][y0+wn][col0][8]; per-icc advance = 4 grp rows
  const u16* pB = imgt + (((size_t)(b * 64 + kg) * HP + (y0 + wn)) * WPAD + col0) * 8;

  f32x4 zero = {0.f, 0.f, 0.f, 0.f};
  f32x4 acc[8][4];
#pragma unroll
  for (int i = 0; i < 8; ++i)
#pragma unroll
    for (int j = 0; j < 4; ++j) acc[i][j] = zero;

  bf16x8 bregE[4], bregO[4];
  bf16x8 AE[8], AO[8];                            // A-frag double buffer

#define STAGE3(slot, iccv, rv) do { \
  _Pragma("unroll") \
  for (int c_ = 0; c_ < 3; ++c_) { \
    int aoff_ = ((3 * (rv) + c_) * 64 + (iccv) * 4) * 4096; \
    async16(awsrc0 + aoff_, (void*)(&abuf[slot][c_][0] + (size_t)tid * 8)); \
    async16(awsrc1 + aoff_, (void*)(&abuf[slot][c_][0] + (size_t)(tid + 512) * 8)); \
  } } while (0)

#define BPF(dst, iccv, tv) do { \
  const u16* pb_ = pB + (size_t)(iccv) * (4 * HPW * 8); \
  dst[0] = *(const bf16x8*)(pb_ + (((tv)/3) * WPAD +  0 + ((tv)%3)) * 8); \
  dst[1] = *(const bf16x8*)(pb_ + (((tv)/3) * WPAD + 16 + ((tv)%3)) * 8); \
  dst[2] = *(const bf16x8*)(pb_ + (((tv)/3) * WPAD + 32 + ((tv)%3)) * 8); \
  dst[3] = *(const bf16x8*)(pb_ + (((tv)/3) * WPAD + 48 + ((tv)%3)) * 8); \
} while (0)

#define ALOAD(AR, slot, c_) do { \
  const u16* ab_ = &abuf[slot][c_][(kg * 256 + wm * 128 + col0) * 8]; \
  _Pragma("unroll") \
  for (int am = 0; am < 8; ++am) AR[am] = *(const bf16x8*)(ab_ + am * 128); \
} while (0)

#define MFMA32(AR, BR) do { \
  __builtin_amdgcn_s_setprio(1); \
  _Pragma("unroll") \
  for (int am = 0; am < 8; ++am) { \
    acc[am][0] = __builtin_amdgcn_mfma_f32_16x16x32_bf16(AR[am], BR[0], acc[am][0], 0, 0, 0); \
    acc[am][1] = __builtin_amdgcn_mfma_f32_16x16x32_bf16(AR[am], BR[1], acc[am][1], 0, 0, 0); \
    acc[am][2] = __builtin_amdgcn_mfma_f32_16x16x32_bf16(AR[am], BR[2], acc[am][2], 0, 0, 0); \
    acc[am][3] = __builtin_amdgcn_mfma_f32_16x16x32_bf16(AR[am], BR[3], acc[am][3], 0, 0, 0); \
  } \
  __builtin_amdgcn_s_setprio(0); \
} while (0)

// group g (0..5) within an ii (2 icc); taps j = 3g..3g+2; B parity B0,B1,B0.
// A-frags register-double-buffered: tap c+1's ds_reads issue during tap c's
// MFMA sprint; only the group-head ALOAD (post-barrier) has exposed latency.
#define GROUP(g, B0, B1) do { \
  ALOAD(AE, ((g) & 1), 0); \
  if (ii < 7 || (g) < 5) STAGE3((((g) + 1) & 1), ii2 + ((g) + 1) / 3, ((g) + 1) % 3); \
  BPF(B1, ii2 + (3 * (g) + 1) / 9, (3 * (g) + 1) % 9); \
  ALOAD(AO, ((g) & 1), 1); \
  MFMA32(AE, B0); \
  BPF(B0, ii2 + (3 * (g) + 2) / 9, (3 * (g) + 2) % 9); \
  ALOAD(AE, ((g) & 1), 2); \
  MFMA32(AO, B1); \
  if (ii < 7 || 3 * (g) + 3 < 18) BPF(B1, ii2 + (3 * (g) + 3) / 9, (3 * (g) + 3) % 9); \
  MFMA32(AE, B0); \
  asm volatile("s_waitcnt vmcnt(12)" ::: "memory"); \
  __builtin_amdgcn_s_barrier(); \
  __builtin_amdgcn_sched_barrier(0); \
} while (0)

  // prologue: stage group 0 (slot 0), prefetch B(tap 0)
  {
    const int ii2 = 0;
    STAGE3(0, 0, 0);
    BPF(bregE, 0, 0);
  }
  asm volatile("s_waitcnt vmcnt(4)" ::: "memory");   // 6 stage loads (oldest) done
  __builtin_amdgcn_s_barrier();
  __builtin_amdgcn_sched_barrier(0);

  for (int ii = 0; ii < 8; ++ii) {                   // 2 icc (= 6 groups, 18 taps)
    const int ii2 = 2 * ii;
    GROUP(0, bregE, bregO);
    GROUP(1, bregO, bregE);
    GROUP(2, bregE, bregO);
    GROUP(3, bregO, bregE);
    GROUP(4, bregE, bregO);
    GROUP(5, bregO, bregE);
  }
#undef GROUP
#undef MFMA32
#undef ALOAD
#undef BPF
#undef STAGE3

  int y = y0 + wn;
#pragma unroll
  for (int am = 0; am < 8; ++am) {
    int o = obase + wm * 128 + am * 16 + kg * 4;    // row = (lane>>4)*4 + reg
#pragma unroll
    for (int an = 0; an < 4; ++an) {
      int x = an * 16 + col0;                        // col = lane&15
      float* op = out + (((size_t)(b * CO + o)) * HH + y) * WW + x;
#pragma unroll
      for (int rg = 0; rg < 4; ++rg)
        op[(size_t)rg * HH * WW] = acc[am][an][rg];
    }
  }
}

// ---------------- Fallback (ws too small): naive but correct ------------------
__global__ void k_naive(const float* __restrict__ img, const float* __restrict__ s,
                        const float* __restrict__ weight, const float* __restrict__ sigma,
                        float* __restrict__ out) {
  int bid = blockIdx.x;          // 8*512*64, 64 threads
  int y = bid & 63; int r = bid >> 6; int o = r & 511; int b = r >> 9;
  int x = threadIdx.x;
  float sig = sigma[b * CO + o];
  float acc = 0.f;
  for (int i = 0; i < CIN; ++i) {
    float m = s[b * CIN + i] + 1.0f;
    const float* wp = weight + ((size_t)o * CIN + i) * 9;
    const float* ip = img + ((size_t)(b * CIN + i)) * HH * WW;
#pragma unroll
    for (int ky = 0; ky < 3; ++ky) {
      int yy = y + ky - 1;
      if (yy < 0 || yy > 63) continue;
#pragma unroll
      for (int kx = 0; kx < 3; ++kx) {
        int xx = x + kx - 1;
        float iv = (xx >= 0 && xx < 64) ? ip[yy * 64 + xx] : 0.f;
        acc += wp[ky * 3 + kx] * m * iv;
      }
    }
  }
  out[((size_t)(b * CO + o) * HH + y) * WW + x] = acc * sig;
}

extern "C" void kernel_launch(void* const* d_in, const int* in_sizes, int n_in,
                              void* d_out, int out_size, void* d_ws, size_t ws_size,
                              hipStream_t stream) {
  const float* img    = (const float*)d_in[0];
  const float* s      = (const float*)d_in[1];
  const float* weight = (const float*)d_in[2];
  float* out = (float*)d_out;
  char* ws = (char*)d_ws;
  float* sigma = (float*)ws;

  if (ws_size >= WS_NEED) {
    u16* wmod = (u16*)(ws + SIG_BYTES);
    u16* imgt = (u16*)(ws + SIG_BYTES + WMOD_BYTES);
    k_sigma<<<512, 256, 0, stream>>>(weight, s, sigma);
    k_wmod<<<256, 256, 0, stream>>>(weight, s, sigma, wmod);
    k_pad<<<528, 256, 0, stream>>>(imgt);
    k_imgt<<<8192, 256, 0, stream>>>(img, imgt);
    k_conv<<<256, 512, 0, stream>>>(wmod, imgt, out);
  } else {
    k_sigma<<<512, 256, 0, stream>>>(weight, s, sigma);
    k_naive<<<BB * CO * HH, 64, 0, stream>>>(img, s, weight, sigma, out);
  }
}

// Round 12
// 178.735 us; speedup vs baseline: 1.2244x; 1.0897x over previous
//
#include <hip/hip_runtime.h>

typedef __attribute__((ext_vector_type(8))) short bf16x8;
typedef __attribute__((ext_vector_type(4))) float f32x4;
typedef __attribute__((ext_vector_type(8))) unsigned short u16x8;
typedef unsigned int u32;
typedef unsigned short u16;

#define CIN 512
#define CO  512
#define HH  64
#define WW  64
#define BB  8
#define HP  66
#define WPAD 68
#define HPW (HP*WPAD)
#define KK  4608  // CIN*9

#define SIG_BYTES  (BB*CO*4)                       // 16384
#define WMOD_ELEMS ((size_t)BB*9*64*CO*8)          // 18,874,368
#define WMOD_BYTES (WMOD_ELEMS*2)                  // 37,748,736
#define IMGT_ELEMS ((size_t)BB*64*HP*WPAD*8)       // 18,382,848  [b][grp64][66][68][8]
#define IMGT_BYTES (IMGT_ELEMS*2)                  // 36,765,696
#define WS_NEED    ((size_t)SIG_BYTES + WMOD_BYTES + IMGT_BYTES)

__device__ __forceinline__ u16 f2bf(float f) {
  union { float f; u32 u; } v; v.f = f;
  u32 r = (v.u + 0x7FFFu + ((v.u >> 16) & 1u)) >> 16;  // RNE
  return (u16)r;
}

// ---------------- K1: sigma[b][o] = rsqrt(sum_i,t (w*(s+1))^2 + eps) ----------
__global__ void k_sigma(const float* __restrict__ weight, const float* __restrict__ s,
                        float* __restrict__ sigma) {
  int o = blockIdx.x;          // 512 blocks
  int tid = threadIdx.x;       // 256 threads
  const float* wrow = weight + (size_t)o * KK;
  float acc[BB];
#pragma unroll
  for (int b = 0; b < BB; ++b) acc[b] = 0.f;
  for (int e = tid; e < KK; e += 256) {
    float w = wrow[e];
    float w2 = w * w;
    int i = e / 9;
#pragma unroll
    for (int b = 0; b < BB; ++b) {
      float m = s[b * CIN + i] + 1.0f;
      acc[b] += w2 * m * m;
    }
  }
#pragma unroll
  for (int b = 0; b < BB; ++b) {
#pragma unroll
    for (int off = 32; off >= 1; off >>= 1)
      acc[b] += __shfl_down(acc[b], off);
  }
  __shared__ float red[4][BB];
  int wv = tid >> 6, ln = tid & 63;
  if (ln == 0) {
#pragma unroll
    for (int b = 0; b < BB; ++b) red[wv][b] = acc[b];
  }
  __syncthreads();
  if (tid < BB) {
    float t = red[0][tid] + red[1][tid] + red[2][tid] + red[3][tid];
    sigma[tid * CO + o] = rsqrtf(t + 1e-8f);
  }
}

// ------------- K2: wmod[b][t][kg][o][8] bf16, LDS-staged coalesced ------------
__global__ __launch_bounds__(256) void k_wmod(const float* __restrict__ weight,
                                              const float* __restrict__ s,
                                              const float* __restrict__ sigma,
                                              u16* __restrict__ wmod) {
  __shared__ float lw[16][577];
  int bid = blockIdx.x;        // 256 = 32 oc * 8 ic
  int oc = bid & 31, ic = bid >> 5;
  int o0 = oc * 16;
  int tid = threadIdx.x;
  const float* wsrc = weight + (size_t)o0 * KK + ic * 576;
#pragma unroll
  for (int k = 0; k < 9; ++k) {
    int f4 = tid + k * 256;            // 0..2303
    int row = f4 / 144;                // 144 float4 per row
    int col = f4 - row * 144;
    float4 v = *(const float4*)(wsrc + (size_t)row * KK + col * 4);
    lw[row][col*4+0]=v.x; lw[row][col*4+1]=v.y; lw[row][col*4+2]=v.z; lw[row][col*4+3]=v.w;
  }
  __syncthreads();
  int o_l = tid & 15, kg_l = (tid >> 4) & 7;
#pragma unroll
  for (int k = 0; k < 36; ++k) {
    int bt = k * 2 + (tid >> 7);       // 0..71
    int b = bt / 9;
    int t = bt - b * 9;
    int o = o0 + o_l;
    float sig = sigma[b * CO + o];
    u16x8 ov;
#pragma unroll
    for (int j = 0; j < 8; ++j) {
      int il = kg_l * 8 + j;
      float w = lw[o_l][il * 9 + t];
      float m = s[b * CIN + ic * 64 + il] + 1.0f;
      ov[j] = f2bf(w * m * sig);
    }
    *(u16x8*)(wmod + ((size_t)(bt * 64 + (ic * 8 + kg_l)) * CO + o) * 8) = ov;
  }
}

// ------------- K3a: zero pad border of imgt [b][grp][66][68][8] --------------
__global__ void k_pad(u16* __restrict__ imgt) {
  int gid = blockIdx.x * 256 + threadIdx.x;   // 528*256 = 135168 vec-stores
  int grp = gid & 63;
  int pos = gid >> 6;                         // 0..2111 = 8b * 264
  int b = pos / 264;
  int pr = pos - b * 264;
  int yp, xp;
  if (pr < 136) { yp = (pr < 68) ? 0 : 65; xp = (pr < 68) ? pr : pr - 68; }
  else { int q = pr - 136; yp = 1 + (q >> 1); xp = (q & 1) ? 67 : 0; }
  u16x8 z = {0,0,0,0,0,0,0,0};
  *(u16x8*)(imgt + (((size_t)(b * 64 + grp) * HP + yp) * WPAD + xp) * 8) = z;
}

// ------------- K3b: imgt[b][grp(64)][yp(66)][xp(68)][8ch] bf16, interior ------
__global__ void k_imgt(const float* __restrict__ img, u16* __restrict__ imgt) {
  int bid = blockIdx.x;        // 8*64*2*8 = 8192 blocks
  int ic = bid & 7;  int r = bid >> 3;
  int xc = r & 1;    r >>= 1;
  int y  = r & 63;   int b = r >> 6;
  int tid = threadIdx.x;
  __shared__ float lt[64][33];
  {
    int ii = tid >> 2, xq = tid & 3;
    const float* src = img + (((size_t)(b * CIN + ic * 64 + ii)) * HH + y) * WW + xc * 32 + xq * 8;
    float4 v0 = *(const float4*)src;
    float4 v1 = *(const float4*)(src + 4);
    int xb = xq * 8;
    lt[ii][xb+0]=v0.x; lt[ii][xb+1]=v0.y; lt[ii][xb+2]=v0.z; lt[ii][xb+3]=v0.w;
    lt[ii][xb+4]=v1.x; lt[ii][xb+5]=v1.y; lt[ii][xb+6]=v1.z; lt[ii][xb+7]=v1.w;
  }
  __syncthreads();
  int xl = tid >> 3, iq = tid & 7;
  u16x8 ov;
#pragma unroll
  for (int j = 0; j < 8; ++j) ov[j] = f2bf(lt[iq*8+j][xl]);
  size_t dst = (((size_t)(b * 64 + ic * 8 + iq) * HP + (y + 1)) * WPAD + (xc * 32 + xl + 1)) * 8;
  *(u16x8*)(imgt + dst) = ov;
}

// --- K4: r5 structure + m201-style barrier-bracketed MFMA phases --------------
__device__ __forceinline__ void async16(const u16* g, void* lds) {
  __builtin_amdgcn_global_load_lds((const __attribute__((address_space(1))) u32*)g,
                                   (__attribute__((address_space(3))) u32*)lds, 16, 0, 0);
}

__global__ __launch_bounds__(512, 2) void k_conv(const u16* __restrict__ wmod,
                                                 const u16* __restrict__ imgt,
                                                 float* __restrict__ out) {
  __shared__ alignas(16) u16 abuf[2][3][8192];   // 2 x (3 taps x 16KB) = 96KB
  int bid0 = blockIdx.x;                          // 256 = 8b * 2ot * 16pt
  int bid  = (bid0 & 7) * 32 + (bid0 >> 3);       // XCD-chunked: each XCD = one b
  int b  = bid >> 5;
  int ot = (bid >> 4) & 1;
  int pt = bid & 15;
  int y0 = pt * 4, obase = ot * 256;
  int tid = threadIdx.x;                          // 512
  int wave = tid >> 6, lane = tid & 63;
  int wm = wave >> 2, wn = wave & 3;              // 2 o-halves x 4 y-rows
  int col0 = lane & 15, kg = lane >> 4;

  // A-stage source: thread covers chunks tid (kg4=tid>>8) and tid+512 (kg4+2)
  const u16* awsrc0 = wmod + (((size_t)(b * 576 + (tid >> 8))) * 512 + obase + (tid & 255)) * 8;
  const u16* awsrc1 = awsrc0 + 2 * 512 * 8;

  // B base: imgt[(b*64+kg)][y0+wn][col0][8]; per-icc advance = 4 grp rows
  const u16* pB = imgt + (((size_t)(b * 64 + kg) * HP + (y0 + wn)) * WPAD + col0) * 8;

  f32x4 zero = {0.f, 0.f, 0.f, 0.f};
  f32x4 acc[8][4];
#pragma unroll
  for (int i = 0; i < 8; ++i)
#pragma unroll
    for (int j = 0; j < 4; ++j) acc[i][j] = zero;

  bf16x8 bregE[4], bregO[4];
  bf16x8 AR[8];                                   // single A-frag set (32 VGPR)

#define STAGE3(slot, iccv, rv) do { \
  _Pragma("unroll") \
  for (int c_ = 0; c_ < 3; ++c_) { \
    int aoff_ = ((3 * (rv) + c_) * 64 + (iccv) * 4) * 4096; \
    async16(awsrc0 + aoff_, (void*)(&abuf[slot][c_][0] + (size_t)tid * 8)); \
    async16(awsrc1 + aoff_, (void*)(&abuf[slot][c_][0] + (size_t)(tid + 512) * 8)); \
  } } while (0)

#define BPF(dst, iccv, tv) do { \
  const u16* pb_ = pB + (size_t)(iccv) * (4 * HPW * 8); \
  dst[0] = *(const bf16x8*)(pb_ + (((tv)/3) * WPAD +  0 + ((tv)%3)) * 8); \
  dst[1] = *(const bf16x8*)(pb_ + (((tv)/3) * WPAD + 16 + ((tv)%3)) * 8); \
  dst[2] = *(const bf16x8*)(pb_ + (((tv)/3) * WPAD + 32 + ((tv)%3)) * 8); \
  dst[3] = *(const bf16x8*)(pb_ + (((tv)/3) * WPAD + 48 + ((tv)%3)) * 8); \
} while (0)

#define ALOAD(slot, c_) do { \
  const u16* ab_ = &abuf[slot][c_][(kg * 256 + wm * 128 + col0) * 8]; \
  _Pragma("unroll") \
  for (int am = 0; am < 8; ++am) AR[am] = *(const bf16x8*)(ab_ + am * 128); \
} while (0)

#define MFMA32(BR) do { \
  __builtin_amdgcn_s_setprio(1); \
  _Pragma("unroll") \
  for (int am = 0; am < 8; ++am) { \
    acc[am][0] = __builtin_amdgcn_mfma_f32_16x16x32_bf16(AR[am], BR[0], acc[am][0], 0, 0, 0); \
    acc[am][1] = __builtin_amdgcn_mfma_f32_16x16x32_bf16(AR[am], BR[1], acc[am][1], 0, 0, 0); \
    acc[am][2] = __builtin_amdgcn_mfma_f32_16x16x32_bf16(AR[am], BR[2], acc[am][2], 0, 0, 0); \
    acc[am][3] = __builtin_amdgcn_mfma_f32_16x16x32_bf16(AR[am], BR[3], acc[am][3], 0, 0, 0); \
  } \
  __builtin_amdgcn_s_setprio(0); \
} while (0)

#define PHASE_SYNC() do { \
  __builtin_amdgcn_s_barrier(); \
  asm volatile("s_waitcnt lgkmcnt(0)" ::: "memory"); \
  __builtin_amdgcn_sched_barrier(0); \
} while (0)

// group g (0..5) within an ii (2 icc); taps j = 3g..3g+2; B parity B0,B1,B0.
// m201 bracket: [ds_read | stage | B-load] barrier lgkm0 [MFMA] barrier — waves
// pass the post-issue barrier while the MFMA pipe drains, so the next phase's
// LDS burst overlaps MFMA execution instead of serializing after it.
#define GROUP(g, B0, B1) do { \
  ALOAD(((g) & 1), 0); \
  if (ii < 7 || (g) < 5) STAGE3((((g) + 1) & 1), ii2 + ((g) + 1) / 3, ((g) + 1) % 3); \
  BPF(B1, ii2 + (3 * (g) + 1) / 9, (3 * (g) + 1) % 9); \
  PHASE_SYNC(); \
  MFMA32(B0); \
  __builtin_amdgcn_s_barrier(); \
  ALOAD(((g) & 1), 1); \
  BPF(B0, ii2 + (3 * (g) + 2) / 9, (3 * (g) + 2) % 9); \
  PHASE_SYNC(); \
  MFMA32(B1); \
  __builtin_amdgcn_s_barrier(); \
  ALOAD(((g) & 1), 2); \
  if (ii < 7 || 3 * (g) + 3 < 18) BPF(B1, ii2 + (3 * (g) + 3) / 9, (3 * (g) + 3) % 9); \
  asm volatile("s_waitcnt vmcnt(12)" ::: "memory"); \
  PHASE_SYNC(); \
  MFMA32(B0); \
  __builtin_amdgcn_s_barrier(); \
} while (0)

  // prologue: stage group 0 (slot 0), prefetch B(tap 0)
  {
    const int ii2 = 0;
    STAGE3(0, 0, 0);
    BPF(bregE, 0, 0);
  }
  asm volatile("s_waitcnt vmcnt(4)" ::: "memory");   // 6 stage loads (oldest) done
  __builtin_amdgcn_s_barrier();
  __builtin_amdgcn_sched_barrier(0);

  for (int ii = 0; ii < 8; ++ii) {                   // 2 icc (= 6 groups, 18 taps)
    const int ii2 = 2 * ii;
    GROUP(0, bregE, bregO);
    GROUP(1, bregO, bregE);
    GROUP(2, bregE, bregO);
    GROUP(3, bregO, bregE);
    GROUP(4, bregE, bregO);
    GROUP(5, bregO, bregE);
  }
#undef GROUP
#undef PHASE_SYNC
#undef MFMA32
#undef ALOAD
#undef BPF
#undef STAGE3

  int y = y0 + wn;
#pragma unroll
  for (int am = 0; am < 8; ++am) {
    int o = obase + wm * 128 + am * 16 + kg * 4;    // row = (lane>>4)*4 + reg
#pragma unroll
    for (int an = 0; an < 4; ++an) {
      int x = an * 16 + col0;                        // col = lane&15
      float* op = out + (((size_t)(b * CO + o)) * HH + y) * WW + x;
#pragma unroll
      for (int rg = 0; rg < 4; ++rg)
        op[(size_t)rg * HH * WW] = acc[am][an][rg];
    }
  }
}

// ---------------- Fallback (ws too small): naive but correct ------------------
__global__ void k_naive(const float* __restrict__ img, const float* __restrict__ s,
                        const float* __restrict__ weight, const float* __restrict__ sigma,
                        float* __restrict__ out) {
  int bid = blockIdx.x;          // 8*512*64, 64 threads
  int y = bid & 63; int r = bid >> 6; int o = r & 511; int b = r >> 9;
  int x = threadIdx.x;
  float sig = sigma[b * CO + o];
  float acc = 0.f;
  for (int i = 0; i < CIN; ++i) {
    float m = s[b * CIN + i] + 1.0f;
    const float* wp = weight + ((size_t)o * CIN + i) * 9;
    const float* ip = img + ((size_t)(b * CIN + i)) * HH * WW;
#pragma unroll
    for (int ky = 0; ky < 3; ++ky) {
      int yy = y + ky - 1;
      if (yy < 0 || yy > 63) continue;
#pragma unroll
      for (int kx = 0; kx < 3; ++kx) {
        int xx = x + kx - 1;
        float iv = (xx >= 0 && xx < 64) ? ip[yy * 64 + xx] : 0.f;
        acc += wp[ky * 3 + kx] * m * iv;
      }
    }
  }
  out[((size_t)(b * CO + o) * HH + y) * WW + x] = acc * sig;
}

extern "C" void kernel_launch(void* const* d_in, const int* in_sizes, int n_in,
                              void* d_out, int out_size, void* d_ws, size_t ws_size,
                              hipStream_t stream) {
  const float* img    = (const float*)d_in[0];
  const float* s      = (const float*)d_in[1];
  const float* weight = (const float*)d_in[2];
  float* out = (float*)d_out;
  char* ws = (char*)d_ws;
  float* sigma = (float*)ws;

  if (ws_size >= WS_NEED) {
    u16* wmod = (u16*)(ws + SIG_BYTES);
    u16* imgt = (u16*)(ws + SIG_BYTES + WMOD_BYTES);
    k_sigma<<<512, 256, 0, stream>>>(weight, s, sigma);
    k_wmod<<<256, 256, 0, stream>>>(weight, s, sigma, wmod);
    k_pad<<<528, 256, 0, stream>>>(imgt);
    k_imgt<<<8192, 256, 0, stream>>>(img, imgt);
    k_conv<<<256, 512, 0, stream>>>(wmod, imgt, out);
  } else {
    k_sigma<<<512, 256, 0, stream>>>(weight, s, sigma);
    k_naive<<<BB * CO * HH, 64, 0, stream>>>(img, s, weight, sigma, out);
  }
}

// Round 13
// 177.789 us; speedup vs baseline: 1.2309x; 1.0053x over previous
//
#include <hip/hip_runtime.h>

typedef __attribute__((ext_vector_type(8))) short bf16x8;
typedef __attribute__((ext_vector_type(4))) float f32x4;
typedef __attribute__((ext_vector_type(16))) float f32x16;
typedef __attribute__((ext_vector_type(8))) unsigned short u16x8;
typedef unsigned int u32;
typedef unsigned short u16;

#define CIN 512
#define CO  512
#define HH  64
#define WW  64
#define BB  8
#define HP  66
#define WPAD 68
#define HPW (HP*WPAD)
#define KK  4608  // CIN*9

#define SIG_BYTES  (BB*CO*4)                       // 16384
#define WMOD_ELEMS ((size_t)BB*9*64*CO*8)          // 18,874,368
#define WMOD_BYTES (WMOD_ELEMS*2)                  // 37,748,736
#define IMGT_ELEMS ((size_t)BB*64*HP*WPAD*8)       // 18,382,848  [b][grp64][66][68][8]
#define IMGT_BYTES (IMGT_ELEMS*2)                  // 36,765,696
#define WS_NEED    ((size_t)SIG_BYTES + WMOD_BYTES + IMGT_BYTES)

__device__ __forceinline__ u16 f2bf(float f) {
  union { float f; u32 u; } v; v.f = f;
  u32 r = (v.u + 0x7FFFu + ((v.u >> 16) & 1u)) >> 16;  // RNE
  return (u16)r;
}

// ---------------- K1: sigma[b][o] = rsqrt(sum_i,t (w*(s+1))^2 + eps) ----------
__global__ void k_sigma(const float* __restrict__ weight, const float* __restrict__ s,
                        float* __restrict__ sigma) {
  int o = blockIdx.x;          // 512 blocks
  int tid = threadIdx.x;       // 256 threads
  const float* wrow = weight + (size_t)o * KK;
  float acc[BB];
#pragma unroll
  for (int b = 0; b < BB; ++b) acc[b] = 0.f;
  for (int e = tid; e < KK; e += 256) {
    float w = wrow[e];
    float w2 = w * w;
    int i = e / 9;
#pragma unroll
    for (int b = 0; b < BB; ++b) {
      float m = s[b * CIN + i] + 1.0f;
      acc[b] += w2 * m * m;
    }
  }
#pragma unroll
  for (int b = 0; b < BB; ++b) {
#pragma unroll
    for (int off = 32; off >= 1; off >>= 1)
      acc[b] += __shfl_down(acc[b], off);
  }
  __shared__ float red[4][BB];
  int wv = tid >> 6, ln = tid & 63;
  if (ln == 0) {
#pragma unroll
    for (int b = 0; b < BB; ++b) red[wv][b] = acc[b];
  }
  __syncthreads();
  if (tid < BB) {
    float t = red[0][tid] + red[1][tid] + red[2][tid] + red[3][tid];
    sigma[tid * CO + o] = rsqrtf(t + 1e-8f);
  }
}

// ------------- K2: wmod[b][t][kg][o][8] bf16, LDS-staged coalesced ------------
__global__ __launch_bounds__(256) void k_wmod(const float* __restrict__ weight,
                                              const float* __restrict__ s,
                                              const float* __restrict__ sigma,
                                              u16* __restrict__ wmod) {
  __shared__ float lw[16][577];
  int bid = blockIdx.x;        // 256 = 32 oc * 8 ic
  int oc = bid & 31, ic = bid >> 5;
  int o0 = oc * 16;
  int tid = threadIdx.x;
  const float* wsrc = weight + (size_t)o0 * KK + ic * 576;
#pragma unroll
  for (int k = 0; k < 9; ++k) {
    int f4 = tid + k * 256;            // 0..2303
    int row = f4 / 144;                // 144 float4 per row
    int col = f4 - row * 144;
    float4 v = *(const float4*)(wsrc + (size_t)row * KK + col * 4);
    lw[row][col*4+0]=v.x; lw[row][col*4+1]=v.y; lw[row][col*4+2]=v.z; lw[row][col*4+3]=v.w;
  }
  __syncthreads();
  int o_l = tid & 15, kg_l = (tid >> 4) & 7;
#pragma unroll
  for (int k = 0; k < 36; ++k) {
    int bt = k * 2 + (tid >> 7);       // 0..71
    int b = bt / 9;
    int t = bt - b * 9;
    int o = o0 + o_l;
    float sig = sigma[b * CO + o];
    u16x8 ov;
#pragma unroll
    for (int j = 0; j < 8; ++j) {
      int il = kg_l * 8 + j;
      float w = lw[o_l][il * 9 + t];
      float m = s[b * CIN + ic * 64 + il] + 1.0f;
      ov[j] = f2bf(w * m * sig);
    }
    *(u16x8*)(wmod + ((size_t)(bt * 64 + (ic * 8 + kg_l)) * CO + o) * 8) = ov;
  }
}

// ------------- K3a: zero pad border of imgt [b][grp][66][68][8] --------------
__global__ void k_pad(u16* __restrict__ imgt) {
  int gid = blockIdx.x * 256 + threadIdx.x;   // 528*256 = 135168 vec-stores
  int grp = gid & 63;
  int pos = gid >> 6;                         // 0..2111 = 8b * 264
  int b = pos / 264;
  int pr = pos - b * 264;
  int yp, xp;
  if (pr < 136) { yp = (pr < 68) ? 0 : 65; xp = (pr < 68) ? pr : pr - 68; }
  else { int q = pr - 136; yp = 1 + (q >> 1); xp = (q & 1) ? 67 : 0; }
  u16x8 z = {0,0,0,0,0,0,0,0};
  *(u16x8*)(imgt + (((size_t)(b * 64 + grp) * HP + yp) * WPAD + xp) * 8) = z;
}

// ------------- K3b: imgt[b][grp(64)][yp(66)][xp(68)][8ch] bf16, interior ------
__global__ void k_imgt(const float* __restrict__ img, u16* __restrict__ imgt) {
  int bid = blockIdx.x;        // 8*64*2*8 = 8192 blocks
  int ic = bid & 7;  int r = bid >> 3;
  int xc = r & 1;    r >>= 1;
  int y  = r & 63;   int b = r >> 6;
  int tid = threadIdx.x;
  __shared__ float lt[64][33];
  {
    int ii = tid >> 2, xq = tid & 3;
    const float* src = img + (((size_t)(b * CIN + ic * 64 + ii)) * HH + y) * WW + xc * 32 + xq * 8;
    float4 v0 = *(const float4*)src;
    float4 v1 = *(const float4*)(src + 4);
    int xb = xq * 8;
    lt[ii][xb+0]=v0.x; lt[ii][xb+1]=v0.y; lt[ii][xb+2]=v0.z; lt[ii][xb+3]=v0.w;
    lt[ii][xb+4]=v1.x; lt[ii][xb+5]=v1.y; lt[ii][xb+6]=v1.z; lt[ii][xb+7]=v1.w;
  }
  __syncthreads();
  int xl = tid >> 3, iq = tid & 7;
  u16x8 ov;
#pragma unroll
  for (int j = 0; j < 8; ++j) ov[j] = f2bf(lt[iq*8+j][xl]);
  size_t dst = (((size_t)(b * 64 + ic * 8 + iq) * HP + (y + 1)) * WPAD + (xc * 32 + xl + 1)) * 8;
  *(u16x8*)(imgt + dst) = ov;
}

// ------- K4: r5 structure (3-tap groups, A dbuf LDS) with 32x32x16 MFMA -------
__device__ __forceinline__ void async16(const u16* g, void* lds) {
  __builtin_amdgcn_global_load_lds((const __attribute__((address_space(1))) u32*)g,
                                   (__attribute__((address_space(3))) u32*)lds, 16, 0, 0);
}

__global__ __launch_bounds__(512, 2) void k_conv(const u16* __restrict__ wmod,
                                                 const u16* __restrict__ imgt,
                                                 float* __restrict__ out) {
  __shared__ alignas(16) u16 abuf[2][3][8192];   // 2 x (3 taps x 16KB) = 96KB
                                                  // tile = [4 kgrp8][256 o][8ch]
  int bid0 = blockIdx.x;                          // 256 = 8b * 2ot * 16pt
  int bid  = (bid0 & 7) * 32 + (bid0 >> 3);       // XCD-chunked: each XCD = one b
  int b  = bid >> 5;
  int ot = (bid >> 4) & 1;
  int pt = bid & 15;
  int y0 = pt * 4, obase = ot * 256;
  int tid = threadIdx.x;                          // 512
  int wave = tid >> 6, lane = tid & 63;
  int wm = wave >> 2, wn = wave & 3;              // 2 o-halves x 4 y-rows
  int l31 = lane & 31, lh = lane >> 5;            // 32x32 lane split

  // A-stage source: thread covers chunks tid (kgrp=tid>>8) and tid+512 (kgrp+2)
  const u16* awsrc0 = wmod + (((size_t)(b * 576 + (tid >> 8))) * 512 + obase + (tid & 255)) * 8;
  const u16* awsrc1 = awsrc0 + 2 * 512 * 8;

  // B base: imgt[(b*64 + lh)][y0+wn][l31][8]; channel-grp advance adds HPW*8
  const u16* pB = imgt + (((size_t)(b * 64 + lh) * HP + (y0 + wn)) * WPAD + l31) * 8;

  // A ds_read base (u16 units): [kgrp = kh*2+lh][o = wm*128 + rb*32 + l31][8]
  const int abase16 = (lh * 256 + wm * 128 + l31) * 8;   // kh=0, rb=0

  f32x16 acc[4][2];
#pragma unroll
  for (int i = 0; i < 4; ++i)
#pragma unroll
    for (int j = 0; j < 2; ++j)
#pragma unroll
      for (int e = 0; e < 16; ++e) acc[i][j][e] = 0.f;

  bf16x8 bregE[4], bregO[4];   // [kh0cb0, kh0cb1, kh1cb0, kh1cb1]

#define STAGE3(slot, iccv, rv) do { \
  _Pragma("unroll") \
  for (int c_ = 0; c_ < 3; ++c_) { \
    int aoff_ = ((3 * (rv) + c_) * 64 + (iccv) * 4) * 4096; \
    async16(awsrc0 + aoff_, (void*)(&abuf[slot][c_][0] + (size_t)tid * 8)); \
    async16(awsrc1 + aoff_, (void*)(&abuf[slot][c_][0] + (size_t)(tid + 512) * 8)); \
  } } while (0)

#define BPF(dst, iccv, tv) do { \
  const u16* pb_ = pB + ((size_t)((iccv) * 4) * HPW + ((tv)/3) * WPAD + ((tv)%3)) * 8; \
  dst[0] = *(const bf16x8*)(pb_); \
  dst[1] = *(const bf16x8*)(pb_ + 32 * 8); \
  dst[2] = *(const bf16x8*)(pb_ + 2 * HPW * 8); \
  dst[3] = *(const bf16x8*)(pb_ + (2 * HPW + 32) * 8); \
} while (0)

// one tap: 8 ds_read_b128 (4 rb x 2 kh) + 16 x mfma_32x32x16
#define COMPUTE(slot, c_, BR) do { \
  const u16* ab_ = &abuf[slot][c_][abase16]; \
  bf16x8 a0_[4], a1_[4]; \
  _Pragma("unroll") \
  for (int rb = 0; rb < 4; ++rb) { \
    a0_[rb] = *(const bf16x8*)(ab_ + rb * 256); \
    a1_[rb] = *(const bf16x8*)(ab_ + rb * 256 + 4096); \
  } \
  __builtin_amdgcn_s_setprio(1); \
  _Pragma("unroll") \
  for (int rb = 0; rb < 4; ++rb) { \
    acc[rb][0] = __builtin_amdgcn_mfma_f32_32x32x16_bf16(a0_[rb], BR[0], acc[rb][0], 0, 0, 0); \
    acc[rb][1] = __builtin_amdgcn_mfma_f32_32x32x16_bf16(a0_[rb], BR[1], acc[rb][1], 0, 0, 0); \
  } \
  _Pragma("unroll") \
  for (int rb = 0; rb < 4; ++rb) { \
    acc[rb][0] = __builtin_amdgcn_mfma_f32_32x32x16_bf16(a1_[rb], BR[2], acc[rb][0], 0, 0, 0); \
    acc[rb][1] = __builtin_amdgcn_mfma_f32_32x32x16_bf16(a1_[rb], BR[3], acc[rb][1], 0, 0, 0); \
  } \
  __builtin_amdgcn_s_setprio(0); \
} while (0)

// group g (0..5) within an ii (2 icc); taps j = 3g..3g+2; B parity B0,B1,B0
#define GROUP(g, B0, B1) do { \
  if (ii < 7 || (g) < 5) STAGE3((((g) + 1) & 1), ii2 + ((g) + 1) / 3, ((g) + 1) % 3); \
  BPF(B1, ii2 + (3 * (g) + 1) / 9, (3 * (g) + 1) % 9); \
  COMPUTE(((g) & 1), 0, B0); \
  BPF(B0, ii2 + (3 * (g) + 2) / 9, (3 * (g) + 2) % 9); \
  COMPUTE(((g) & 1), 1, B1); \
  if (ii < 7 || 3 * (g) + 3 < 18) BPF(B1, ii2 + (3 * (g) + 3) / 9, (3 * (g) + 3) % 9); \
  COMPUTE(((g) & 1), 2, B0); \
  asm volatile("s_waitcnt vmcnt(12)" ::: "memory"); \
  __builtin_amdgcn_s_barrier(); \
  __builtin_amdgcn_sched_barrier(0); \
} while (0)

  // prologue: stage group 0 (slot 0), prefetch B(tap 0)
  {
    const int ii2 = 0;
    STAGE3(0, 0, 0);
    BPF(bregE, 0, 0);
  }
  asm volatile("s_waitcnt vmcnt(4)" ::: "memory");   // 6 stage loads (oldest) done
  __builtin_amdgcn_s_barrier();
  __builtin_amdgcn_sched_barrier(0);

  for (int ii = 0; ii < 8; ++ii) {                   // 2 icc (= 6 groups, 18 taps)
    const int ii2 = 2 * ii;
    GROUP(0, bregE, bregO);
    GROUP(1, bregO, bregE);
    GROUP(2, bregE, bregO);
    GROUP(3, bregO, bregE);
    GROUP(4, bregE, bregO);
    GROUP(5, bregO, bregE);
  }
#undef GROUP
#undef COMPUTE
#undef BPF
#undef STAGE3

  // C/D 32x32 layout: col = lane&31, row = (rg&3) + 8*(rg>>2) + 4*(lane>>5)
  int y = y0 + wn;
  int rbase = 4 * lh;
#pragma unroll
  for (int rb = 0; rb < 4; ++rb) {
#pragma unroll
    for (int cb = 0; cb < 2; ++cb) {
      int x = cb * 32 + l31;
#pragma unroll
      for (int rg = 0; rg < 16; ++rg) {
        int o = obase + wm * 128 + rb * 32 + rbase + (rg & 3) + 8 * (rg >> 2);
        out[(((size_t)(b * CO + o)) * HH + y) * WW + x] = acc[rb][cb][rg];
      }
    }
  }
}

// ---------------- Fallback (ws too small): naive but correct ------------------
__global__ void k_naive(const float* __restrict__ img, const float* __restrict__ s,
                        const float* __restrict__ weight, const float* __restrict__ sigma,
                        float* __restrict__ out) {
  int bid = blockIdx.x;          // 8*512*64, 64 threads
  int y = bid & 63; int r = bid >> 6; int o = r & 511; int b = r >> 9;
  int x = threadIdx.x;
  float sig = sigma[b * CO + o];
  float acc = 0.f;
  for (int i = 0; i < CIN; ++i) {
    float m = s[b * CIN + i] + 1.0f;
    const float* wp = weight + ((size_t)o * CIN + i) * 9;
    const float* ip = img + ((size_t)(b * CIN + i)) * HH * WW;
#pragma unroll
    for (int ky = 0; ky < 3; ++ky) {
      int yy = y + ky - 1;
      if (yy < 0 || yy > 63) continue;
#pragma unroll
      for (int kx = 0; kx < 3; ++kx) {
        int xx = x + kx - 1;
        float iv = (xx >= 0 && xx < 64) ? ip[yy * 64 + xx] : 0.f;
        acc += wp[ky * 3 + kx] * m * iv;
      }
    }
  }
  out[((size_t)(b * CO + o) * HH + y) * WW + x] = acc * sig;
}

extern "C" void kernel_launch(void* const* d_in, const int* in_sizes, int n_in,
                              void* d_out, int out_size, void* d_ws, size_t ws_size,
                              hipStream_t stream) {
  const float* img    = (const float*)d_in[0];
  const float* s      = (const float*)d_in[1];
  const float* weight = (const float*)d_in[2];
  float* out = (float*)d_out;
  char* ws = (char*)d_ws;
  float* sigma = (float*)ws;

  if (ws_size >= WS_NEED) {
    u16* wmod = (u16*)(ws + SIG_BYTES);
    u16* imgt = (u16*)(ws + SIG_BYTES + WMOD_BYTES);
    k_sigma<<<512, 256, 0, stream>>>(weight, s, sigma);
    k_wmod<<<256, 256, 0, stream>>>(weight, s, sigma, wmod);
    k_pad<<<528, 256, 0, stream>>>(imgt);
    k_imgt<<<8192, 256, 0, stream>>>(img, imgt);
    k_conv<<<256, 512, 0, stream>>>(wmod, imgt, out);
  } else {
    k_sigma<<<512, 256, 0, stream>>>(weight, s, sigma);
    k_naive<<<BB * CO * HH, 64, 0, stream>>>(img, s, weight, sigma, out);
  }
}